// Round 1
// baseline (463.100 us; speedup 1.0000x reference)
//
#include <hip/hip_runtime.h>

typedef unsigned short u16;
typedef __bf16 bf16x8 __attribute__((ext_vector_type(8)));
typedef float f32x4 __attribute__((ext_vector_type(4)));

__device__ __forceinline__ u16 f2bf(float f) {
  union { float f; unsigned u; } v; v.f = f;
  unsigned r = (v.u + 0x7FFFu + ((v.u >> 16) & 1u)) >> 16;
  return (u16)r;
}
__device__ __forceinline__ float bf2f(u16 h) {
  union { unsigned u; float f; } v; v.u = ((unsigned)h) << 16;
  return v.f;
}

__device__ __forceinline__ void load_lds16(const void* g, void* l) {
  __builtin_amdgcn_global_load_lds((__attribute__((address_space(1))) void*)(g),
                                   (__attribute__((address_space(3))) void*)(l), 16, 0, 0);
}

// ---------------------------------------------------------------------------
// Generic bf16 A[M,K] x Bt[N,K] GEMM (K-contiguous both operands), fp32 acc.
// modes: 0 = fp32 store, 1 = elu(v)+1 fp32, 2 = v/1024 fp32,
//        3 = bf16 store, 4 = relu -> bf16
// ---------------------------------------------------------------------------
__global__ __launch_bounds__(256) void gemm_bt_kernel(
    const u16* __restrict__ A, const u16* __restrict__ Bt,
    float* __restrict__ Cf, u16* __restrict__ Cb,
    int M, int N, int K, int mode)
{
  __shared__ __attribute__((aligned(16))) u16 lA[128 * 32];
  __shared__ __attribute__((aligned(16))) u16 lB[128 * 32];
  const int tid  = threadIdx.x;
  const int wave = tid >> 6;
  const int lane = tid & 63;
  const int wi = wave >> 1, wj = wave & 1;
  const int m0 = blockIdx.x * 128;
  const int n0 = blockIdx.y * 128;
  const int srow = lane >> 2;        // staging row within 16-row chunk
  const int skc  = (lane & 3) * 8;   // staging k offset (ushorts)
  const int lm = lane & 15;
  const int kq = (lane >> 4) * 8;

  f32x4 acc[4][4];
  const f32x4 zv = {0.f, 0.f, 0.f, 0.f};
#pragma unroll
  for (int i = 0; i < 4; ++i)
#pragma unroll
    for (int j = 0; j < 4; ++j) acc[i][j] = zv;

  const int kTiles = K >> 5;
  for (int kt = 0; kt < kTiles; ++kt) {
    __syncthreads();
#pragma unroll
    for (int t = 0; t < 2; ++t) {
      const int ci = wave * 2 + t;
      const u16* ga = A + (size_t)(m0 + ci * 16 + srow) * K + kt * 32 + skc;
      load_lds16(ga, &lA[ci * 512]);
      const u16* gb = Bt + (size_t)(n0 + ci * 16 + srow) * K + kt * 32 + skc;
      load_lds16(gb, &lB[ci * 512]);
    }
    asm volatile("s_waitcnt vmcnt(0)" ::: "memory");
    __syncthreads();
    bf16x8 af[4], bfr[4];
#pragma unroll
    for (int i = 0; i < 4; ++i)
      af[i] = *(const bf16x8*)&lA[(wi * 64 + i * 16 + lm) * 32 + kq];
#pragma unroll
    for (int j = 0; j < 4; ++j)
      bfr[j] = *(const bf16x8*)&lB[(wj * 64 + j * 16 + lm) * 32 + kq];
#pragma unroll
    for (int i = 0; i < 4; ++i)
#pragma unroll
      for (int j = 0; j < 4; ++j)
        acc[i][j] = __builtin_amdgcn_mfma_f32_16x16x32_bf16(af[i], bfr[j], acc[i][j], 0, 0, 0);
  }

  const int lq = lane >> 4;
#pragma unroll
  for (int i = 0; i < 4; ++i) {
#pragma unroll
    for (int j = 0; j < 4; ++j) {
      const int col  = n0 + wj * 64 + j * 16 + lm;
      const int row0 = m0 + wi * 64 + i * 16 + lq * 4;
#pragma unroll
      for (int r = 0; r < 4; ++r) {
        float v = acc[i][j][r];
        const size_t idx = (size_t)(row0 + r) * N + col;
        if (mode == 0)      Cf[idx] = v;
        else if (mode == 1) Cf[idx] = (v > 0.f) ? (v + 1.f) : __expf(v);
        else if (mode == 2) Cf[idx] = v * (1.f / 1024.f);
        else if (mode == 3) Cb[idx] = f2bf(v);
        else                Cb[idx] = f2bf(v > 0.f ? v : 0.f);
      }
    }
  }
}

// ---------------------------------------------------------------------------
// Weight transpose + bf16 cast: w[K][N] fp32 -> wt[N][K] bf16 (64x64 tiles)
// ---------------------------------------------------------------------------
__global__ __launch_bounds__(256) void transpose_w_kernel(
    const float* __restrict__ wq, const float* __restrict__ wk,
    const float* __restrict__ wv, const float* __restrict__ wm,
    const float* __restrict__ w1, const float* __restrict__ w2,
    u16* __restrict__ oq, u16* __restrict__ okk, u16* __restrict__ ov,
    u16* __restrict__ om, u16* __restrict__ o1, u16* __restrict__ o2)
{
  __shared__ float ts[64][65];
  int bid = blockIdx.x;
  const float* src; u16* dst; int K, N, t;
  if (bid < 64) {
    int wsel = bid >> 4; t = bid & 15; K = 256; N = 256;
    src = wsel == 0 ? wq : wsel == 1 ? wk : wsel == 2 ? wv : wm;
    dst = wsel == 0 ? oq : wsel == 1 ? okk : wsel == 2 ? ov : om;
  } else if (bid < 128) { t = bid - 64; K = 512; N = 512; src = w1; dst = o1; }
  else                  { t = bid - 128; K = 512; N = 256; src = w2; dst = o2; }
  const int ntn = N >> 6;
  const int tn = t % ntn, tk = t / ntn;
  const int tid = threadIdx.x, ln = tid & 63, lrr = tid >> 6;
  for (int k = 0; k < 64; k += 4)
    ts[k + lrr][ln] = src[(size_t)(tk * 64 + k + lrr) * N + tn * 64 + ln];
  __syncthreads();
  for (int k = 0; k < 64; k += 4)
    dst[(size_t)(tn * 64 + k + lrr) * K + tk * 64 + ln] = f2bf(ts[ln][k + lrr]);
}

// ---------------------------------------------------------------------------
// Fused 4x4 maxpool (NCHW) + layernorm over C -> bf16 rows [b*1024+ph*32+pw][256]
// grid: (32 ph, 4 b, 2 tensor-select), block 256
// ---------------------------------------------------------------------------
__global__ __launch_bounds__(256) void pool_ln_kernel(
    const float* __restrict__ x, const float* __restrict__ src,
    const float* __restrict__ g, const float* __restrict__ bb,
    u16* __restrict__ qout, u16* __restrict__ sout)
{
  __shared__ float pool[256 * 33];
  __shared__ float redA[8][32];
  __shared__ float redB[8][32];
  __shared__ float stat_m[32];
  __shared__ float stat_r[32];
  const int ph = blockIdx.x, b = blockIdx.y;
  const float* in = blockIdx.z ? src : x;
  u16* out = blockIdx.z ? sout : qout;
  const int tid = threadIdx.x;
  const int pw = tid & 31, cg = tid >> 5;   // cg 0..7
  for (int kk = 0; kk < 32; ++kk) {
    const int c = cg * 32 + kk;
    const float* base = in + (((size_t)b * 256 + c) * 128 + ph * 4) * 128 + pw * 4;
    float4 v0 = *(const float4*)(base);
    float4 v1 = *(const float4*)(base + 128);
    float4 v2 = *(const float4*)(base + 256);
    float4 v3 = *(const float4*)(base + 384);
    float m = fmaxf(fmaxf(fmaxf(v0.x, v0.y), fmaxf(v0.z, v0.w)),
                    fmaxf(fmaxf(v1.x, v1.y), fmaxf(v1.z, v1.w)));
    m = fmaxf(m, fmaxf(fmaxf(v2.x, v2.y), fmaxf(v2.z, v2.w)));
    m = fmaxf(m, fmaxf(fmaxf(v3.x, v3.y), fmaxf(v3.z, v3.w)));
    pool[c * 33 + pw] = m;
  }
  __syncthreads();
  float s = 0.f, s2 = 0.f;
  for (int i = 0; i < 32; ++i) {
    float v = pool[(cg * 32 + i) * 33 + pw];
    s += v; s2 += v * v;
  }
  redA[cg][pw] = s; redB[cg][pw] = s2;
  __syncthreads();
  if (tid < 32) {
    float ss = 0.f, ss2 = 0.f;
    for (int i = 0; i < 8; ++i) { ss += redA[i][tid]; ss2 += redB[i][tid]; }
    float mean = ss * (1.f / 256.f);
    float var = ss2 * (1.f / 256.f) - mean * mean;
    stat_m[tid] = mean;
    stat_r[tid] = rsqrtf(var + 1e-5f);
  }
  __syncthreads();
  const float gc = g[tid], bc = bb[tid];
  const size_t rowbase = ((size_t)b * 1024 + ph * 32) * 256;
  for (int p = 0; p < 32; ++p) {
    float v = (pool[tid * 33 + p] - stat_m[p]) * stat_r[p] * gc + bc;
    out[rowbase + (size_t)p * 256 + tid] = f2bf(v);
  }
}

// ---------------------------------------------------------------------------
// KV[d][v] = sum_s Kp[s,d]*Vn[s,v];  Ksum[d] = sum_s Kp[s,d]   per (b,h)
// grid (8 h, 4 b), block 256. Out layout per (b,h): 1024 KV + 32 ksum floats.
// ---------------------------------------------------------------------------
__global__ __launch_bounds__(256) void kv_kernel(
    const float* __restrict__ Kp, const float* __restrict__ Vn,
    float* __restrict__ kvbuf)
{
  __shared__ float kch[128 * 33];
  __shared__ float vch[128 * 33];
  const int h = blockIdx.x, b = blockIdx.y;
  const int tid = threadIdx.x;
  const int d = tid & 31, sl = tid >> 5;
  const int v = tid & 31, dp = tid >> 5;
  float a0 = 0.f, a1 = 0.f, a2 = 0.f, a3 = 0.f, ks = 0.f;
  for (int ch = 0; ch < 8; ++ch) {
    __syncthreads();
    for (int ss = 0; ss < 16; ++ss) {
      const int srow = ch * 128 + ss * 8 + sl;
      const size_t gi = ((size_t)b * 1024 + srow) * 256 + h * 32 + d;
      kch[(ss * 8 + sl) * 33 + d] = Kp[gi];
      vch[(ss * 8 + sl) * 33 + d] = Vn[gi];
    }
    __syncthreads();
    for (int s = 0; s < 128; ++s) {
      const float vv = vch[s * 33 + v];
      a0 += kch[s * 33 + dp] * vv;
      a1 += kch[s * 33 + dp + 8] * vv;
      a2 += kch[s * 33 + dp + 16] * vv;
      a3 += kch[s * 33 + dp + 24] * vv;
    }
    if (tid < 32)
      for (int s = 0; s < 128; ++s) ks += kch[s * 33 + tid];
  }
  float* outp = kvbuf + ((size_t)b * 8 + h) * 1056;
  outp[(dp) * 32 + v]      = a0;
  outp[(dp + 8) * 32 + v]  = a1;
  outp[(dp + 16) * 32 + v] = a2;
  outp[(dp + 24) * 32 + v] = a3;
  if (tid < 32) outp[1024 + tid] = ks;
}

// ---------------------------------------------------------------------------
// msg[l,h,v] = (Qp[l]·KV[:,v]) * 1024 / (Qp[l]·Ksum + 1e-6) -> bf16
// grid (16 l-chunks, 8 h, 4 b), block 256 (8 l x 32 v per pass)
// ---------------------------------------------------------------------------
__global__ __launch_bounds__(256) void msg_kernel(
    const float* __restrict__ Qp, const float* __restrict__ kvbuf,
    u16* __restrict__ msg2)
{
  __shared__ float kv[32 * 33];
  __shared__ float ksum[32];
  __shared__ float qch[8 * 33];
  const int lc = blockIdx.x, h = blockIdx.y, b = blockIdx.z;
  const int tid = threadIdx.x;
  const float* kvp = kvbuf + ((size_t)b * 8 + h) * 1056;
  for (int i = tid; i < 1024; i += 256) kv[(i >> 5) * 33 + (i & 31)] = kvp[i];
  if (tid < 32) ksum[tid] = kvp[1024 + tid];
  const int d = tid & 31, lr = tid >> 5;
  const int v = tid & 31;
  for (int ps = 0; ps < 8; ++ps) {
    __syncthreads();
    const int l = lc * 64 + ps * 8 + lr;
    qch[lr * 33 + d] = Qp[((size_t)b * 1024 + l) * 256 + h * 32 + d];
    __syncthreads();
    float dot = 0.f, zden = 0.f;
    for (int dd = 0; dd < 32; ++dd) {
      const float q = qch[lr * 33 + dd];
      dot  += q * kv[dd * 33 + v];
      zden += q * ksum[dd];
    }
    const float m = dot * (1024.f / (zden + 1e-6f));
    msg2[((size_t)b * 1024 + l) * 256 + h * 32 + v] = f2bf(m);
  }
}

// ---------------------------------------------------------------------------
// x NCHW fp32 -> A[pix][0:256] bf16 (NHWC). grid (2 jc, 4 cc, 128*nb), blk 256
// ---------------------------------------------------------------------------
__global__ __launch_bounds__(256) void trans_kernel(
    const float* __restrict__ x, u16* __restrict__ Ab, int b0)
{
  __shared__ float ts[64][65];
  const int jc = blockIdx.x, cc = blockIdx.y, iz = blockIdx.z;
  const int localb = iz >> 7;
  const int b = b0 + localb;
  const int i = iz & 127;
  const int tid = threadIdx.x, ln = tid & 63, lrr = tid >> 6;
  const float* xp = x + (size_t)b * 256 * 16384;
  for (int k = 0; k < 64; k += 4) {
    const int c = cc * 64 + k + lrr;
    ts[k + lrr][ln] = xp[((size_t)c * 128 + i) * 128 + jc * 64 + ln];
  }
  __syncthreads();
  for (int k = 0; k < 64; k += 4) {
    const int j = jc * 64 + k + lrr;
    const size_t row = (size_t)localb * 16384 + (size_t)i * 128 + j;
    Ab[row * 512 + cc * 64 + ln] = f2bf(ts[ln][k + lrr]);
  }
}

// ---------------------------------------------------------------------------
// Bilinear 4x upsample (half-pixel, edge-clamped) of merged[b*1024+py*32+px][256]
// -> A[pix][256:512] bf16. grid (2 jc, 128*nb), block 256 (c = tid)
// ---------------------------------------------------------------------------
__global__ __launch_bounds__(256) void up_kernel(
    const u16* __restrict__ merged, u16* __restrict__ Ab, int b0)
{
  const int jc = blockIdx.x, iz = blockIdx.y;
  const int localb = iz >> 7;
  const int b = b0 + localb;
  const int i = iz & 127;
  const int tid = threadIdx.x;
  const float sy = 0.25f * i - 0.375f;
  const float fy = floorf(sy);
  const float wy = sy - fy;
  const int y0 = max(0, min(31, (int)fy));
  const int y1 = max(0, min(31, (int)fy + 1));
  const u16* mb = merged + (size_t)b * 1024 * 256;
  for (int p = 0; p < 64; ++p) {
    const int j = jc * 64 + p;
    const float sx = 0.25f * j - 0.375f;
    const float fx = floorf(sx);
    const float wx = sx - fx;
    const int x0 = max(0, min(31, (int)fx));
    const int x1 = max(0, min(31, (int)fx + 1));
    const u16* r00 = mb + ((size_t)y0 * 32 + x0) * 256;
    const u16* r01 = mb + ((size_t)y0 * 32 + x1) * 256;
    const u16* r10 = mb + ((size_t)y1 * 32 + x0) * 256;
    const u16* r11 = mb + ((size_t)y1 * 32 + x1) * 256;
    const float v = (1.f - wy) * ((1.f - wx) * bf2f(r00[tid]) + wx * bf2f(r01[tid]))
                  +        wy  * ((1.f - wx) * bf2f(r10[tid]) + wx * bf2f(r11[tid]));
    const size_t row = (size_t)localb * 16384 + (size_t)i * 128 + j;
    Ab[row * 512 + 256 + tid] = f2bf(v);
  }
}

// ---------------------------------------------------------------------------
// LayerNorm(m) over C=256 + residual: out[b,c,i,j] = x + LN(m)[pix,c]
// grid (2 jc, 128*nb), block 256. Coalesced NCHW writes (lanes along j).
// ---------------------------------------------------------------------------
__global__ __launch_bounds__(256) void ln_res_kernel(
    const float* __restrict__ m, const float* __restrict__ x,
    const float* __restrict__ g, const float* __restrict__ bb,
    float* __restrict__ out, int b0)
{
  __shared__ float sm[64 * 257];
  __shared__ float redA[64][4];
  __shared__ float redB[64][4];
  __shared__ float stat_m[64];
  __shared__ float stat_r[64];
  const int jc = blockIdx.x, iz = blockIdx.y;
  const int localb = iz >> 7;
  const int b = b0 + localb;
  const int i = iz & 127;
  const int tid = threadIdx.x;
  for (int p = 0; p < 64; ++p) {
    const size_t row = (size_t)localb * 16384 + (size_t)i * 128 + jc * 64 + p;
    sm[p * 257 + tid] = m[row * 256 + tid];
  }
  __syncthreads();
  {
    const int p = tid >> 2, q = tid & 3;
    float s = 0.f, s2 = 0.f;
    for (int k = 0; k < 64; ++k) {
      const float v = sm[p * 257 + q * 64 + k];
      s += v; s2 += v * v;
    }
    redA[p][q] = s; redB[p][q] = s2;
  }
  __syncthreads();
  if (tid < 64) {
    const float ss = redA[tid][0] + redA[tid][1] + redA[tid][2] + redA[tid][3];
    const float qq = redB[tid][0] + redB[tid][1] + redB[tid][2] + redB[tid][3];
    const float mean = ss * (1.f / 256.f);
    const float var = qq * (1.f / 256.f) - mean * mean;
    stat_m[tid] = mean;
    stat_r[tid] = rsqrtf(var + 1e-5f);
  }
  __syncthreads();
  const int p = tid & 63, cgr = tid >> 6;
  const int j = jc * 64 + p;
  const float mu = stat_m[p], rs = stat_r[p];
  for (int k = 0; k < 64; ++k) {
    const int c = cgr * 64 + k;
    const float v = (sm[p * 257 + c] - mu) * rs * g[c] + bb[c];
    const size_t oi = (((size_t)b * 256 + c) * 128 + i) * 128 + j;
    out[oi] = x[oi] + v;
  }
}

// ---------------------------------------------------------------------------
extern "C" void kernel_launch(void* const* d_in, const int* in_sizes, int n_in,
                              void* d_out, int out_size, void* d_ws, size_t ws_size,
                              hipStream_t stream) {
  (void)in_sizes; (void)n_in; (void)out_size;
  const float* x   = (const float*)d_in[0];
  const float* src = (const float*)d_in[1];
  const float* n1g = (const float*)d_in[2];
  const float* n1b = (const float*)d_in[3];
  const float* w_q = (const float*)d_in[4];
  const float* w_k = (const float*)d_in[5];
  const float* w_v = (const float*)d_in[6];
  const float* w_m = (const float*)d_in[7];
  const float* w1  = (const float*)d_in[8];
  const float* w2  = (const float*)d_in[9];
  const float* n2g = (const float*)d_in[10];
  const float* n2b = (const float*)d_in[11];
  float* out = (float*)d_out;

  char* ws = (char*)d_ws;
  size_t off = 0;
  auto alloc = [&](size_t bytes) -> void* {
    void* p = ws + off;
    off = (off + bytes + 255) & ~(size_t)255;
    return p;
  };
  u16* wqT = (u16*)alloc(256 * 256 * 2);
  u16* wkT = (u16*)alloc(256 * 256 * 2);
  u16* wvT = (u16*)alloc(256 * 256 * 2);
  u16* wmT = (u16*)alloc(256 * 256 * 2);
  u16* w1T = (u16*)alloc(512 * 512 * 2);
  u16* w2T = (u16*)alloc(256 * 512 * 2);
  u16* qbf = (u16*)alloc((size_t)4096 * 256 * 2);
  u16* sbf = (u16*)alloc((size_t)4096 * 256 * 2);
  float* Qp = (float*)alloc((size_t)4096 * 256 * 4);
  float* Kp = (float*)alloc((size_t)4096 * 256 * 4);
  float* Vn = (float*)alloc((size_t)4096 * 256 * 4);
  float* kvb = (float*)alloc((size_t)32 * 1056 * 4);
  u16* msg2   = (u16*)alloc((size_t)4096 * 256 * 2);
  u16* merged = (u16*)alloc((size_t)4096 * 256 * 2);

  // batch factor for the MLP stage, chosen from remaining ws
  size_t remain = (ws_size > off) ? ws_size - off : 0;
  auto need = [](int nb) { return (size_t)nb * 16384 * 1024 * 2 + 1024; }; // A + hidden
  int nb = (remain >= need(4)) ? 4 : (remain >= need(2)) ? 2 : 1;
  u16* Ab  = (u16*)alloc((size_t)nb * 16384 * 512 * 2);
  u16* hid = (u16*)alloc((size_t)nb * 16384 * 512 * 2);
  float* mbuf = (float*)Ab;  // alias: Ab dead once hidden is computed

  transpose_w_kernel<<<dim3(160), dim3(256), 0, stream>>>(
      w_q, w_k, w_v, w_m, w1, w2, wqT, wkT, wvT, wmT, w1T, w2T);

  pool_ln_kernel<<<dim3(32, 4, 2), dim3(256), 0, stream>>>(
      x, src, n1g, n1b, qbf, sbf);

  gemm_bt_kernel<<<dim3(32, 2), dim3(256), 0, stream>>>(
      qbf, wqT, Qp, nullptr, 4096, 256, 256, 1);
  gemm_bt_kernel<<<dim3(32, 2), dim3(256), 0, stream>>>(
      sbf, wkT, Kp, nullptr, 4096, 256, 256, 1);
  gemm_bt_kernel<<<dim3(32, 2), dim3(256), 0, stream>>>(
      sbf, wvT, Vn, nullptr, 4096, 256, 256, 2);

  kv_kernel<<<dim3(8, 4), dim3(256), 0, stream>>>(Kp, Vn, kvb);
  msg_kernel<<<dim3(16, 8, 4), dim3(256), 0, stream>>>(Qp, kvb, msg2);

  gemm_bt_kernel<<<dim3(32, 2), dim3(256), 0, stream>>>(
      msg2, wmT, nullptr, merged, 4096, 256, 256, 3);

  for (int b0 = 0; b0 < 4; b0 += nb) {
    trans_kernel<<<dim3(2, 4, 128 * nb), dim3(256), 0, stream>>>(x, Ab, b0);
    up_kernel<<<dim3(2, 128 * nb), dim3(256), 0, stream>>>(merged, Ab, b0);
    gemm_bt_kernel<<<dim3(nb * 128, 4), dim3(256), 0, stream>>>(
        Ab, w1T, nullptr, hid, nb * 16384, 512, 512, 4);
    gemm_bt_kernel<<<dim3(nb * 128, 2), dim3(256), 0, stream>>>(
        hid, w2T, mbuf, nullptr, nb * 16384, 256, 512, 0);
    ln_res_kernel<<<dim3(2, 128 * nb), dim3(256), 0, stream>>>(
        mbuf, x, n2g, n2b, out, b0);
  }
}

// Round 2
// 375.176 us; speedup vs baseline: 1.2344x; 1.2344x over previous
//
#include <hip/hip_runtime.h>

typedef unsigned short u16;
typedef __bf16 bf16x8 __attribute__((ext_vector_type(8)));
typedef float f32x4 __attribute__((ext_vector_type(4)));
typedef float f32x16 __attribute__((ext_vector_type(16)));

__device__ __forceinline__ u16 f2bf(float f) {
  union { float f; unsigned u; } v; v.f = f;
  unsigned r = (v.u + 0x7FFFu + ((v.u >> 16) & 1u)) >> 16;
  return (u16)r;
}
__device__ __forceinline__ float bf2f(u16 h) {
  union { unsigned u; float f; } v; v.u = ((unsigned)h) << 16;
  return v.f;
}

__device__ __forceinline__ void load_lds16(const void* g, void* l) {
  __builtin_amdgcn_global_load_lds((__attribute__((address_space(1))) void*)(g),
                                   (__attribute__((address_space(3))) void*)(l), 16, 0, 0);
}

// ---------------------------------------------------------------------------
// Small 128x128-tile bf16 GEMM body (16x16x32), used for QKV + merge.
// modes: 1 = elu(v)+1 fp32, 2 = v/1024 fp32, 3 = bf16 store
// ---------------------------------------------------------------------------
__device__ __forceinline__ void gemm128(
    const u16* __restrict__ A, const u16* __restrict__ Bt,
    float* __restrict__ Cf, u16* __restrict__ Cb,
    int N, int K, int mode,
    u16* lA, u16* lB)
{
  const int tid  = threadIdx.x;
  const int wave = tid >> 6;
  const int lane = tid & 63;
  const int wi = wave >> 1, wj = wave & 1;
  const int m0 = blockIdx.x * 128;
  const int n0 = blockIdx.y * 128;
  const int srow = lane >> 2;
  const int skc  = (lane & 3) * 8;
  const int lm = lane & 15;
  const int kq = (lane >> 4) * 8;

  f32x4 acc[4][4];
#pragma unroll
  for (int i = 0; i < 4; ++i)
#pragma unroll
    for (int j = 0; j < 4; ++j)
#pragma unroll
      for (int e = 0; e < 4; ++e) acc[i][j][e] = 0.f;

  const int kTiles = K >> 5;
  for (int kt = 0; kt < kTiles; ++kt) {
    __syncthreads();
#pragma unroll
    for (int t = 0; t < 2; ++t) {
      const int ci = wave * 2 + t;
      const u16* ga = A + (size_t)(m0 + ci * 16 + srow) * K + kt * 32 + skc;
      load_lds16(ga, &lA[ci * 512]);
      const u16* gb = Bt + (size_t)(n0 + ci * 16 + srow) * K + kt * 32 + skc;
      load_lds16(gb, &lB[ci * 512]);
    }
    asm volatile("s_waitcnt vmcnt(0)" ::: "memory");
    __syncthreads();
    bf16x8 af[4], bfr[4];
#pragma unroll
    for (int i = 0; i < 4; ++i)
      af[i] = *(const bf16x8*)&lA[(wi * 64 + i * 16 + lm) * 32 + kq];
#pragma unroll
    for (int j = 0; j < 4; ++j)
      bfr[j] = *(const bf16x8*)&lB[(wj * 64 + j * 16 + lm) * 32 + kq];
#pragma unroll
    for (int i = 0; i < 4; ++i)
#pragma unroll
      for (int j = 0; j < 4; ++j)
        acc[i][j] = __builtin_amdgcn_mfma_f32_16x16x32_bf16(af[i], bfr[j], acc[i][j], 0, 0, 0);
  }

  const int lq = lane >> 4;
#pragma unroll
  for (int i = 0; i < 4; ++i) {
#pragma unroll
    for (int j = 0; j < 4; ++j) {
      const int col  = n0 + wj * 64 + j * 16 + lm;
      const int row0 = m0 + wi * 64 + i * 16 + lq * 4;
#pragma unroll
      for (int r = 0; r < 4; ++r) {
        float v = acc[i][j][r];
        const size_t idx = (size_t)(row0 + r) * N + col;
        if (mode == 1)      Cf[idx] = (v > 0.f) ? (v + 1.f) : __expf(v);
        else if (mode == 2) Cf[idx] = v * (1.f / 1024.f);
        else                Cb[idx] = f2bf(v);
      }
    }
  }
}

// QKV: grid (32, 2, 3)
__global__ __launch_bounds__(256) void qkv_kernel(
    const u16* __restrict__ qbf, const u16* __restrict__ sbf,
    const u16* __restrict__ wqT, const u16* __restrict__ wkT, const u16* __restrict__ wvT,
    float* __restrict__ Qp, float* __restrict__ Kp, float* __restrict__ Vn)
{
  __shared__ __attribute__((aligned(16))) u16 lA[128 * 32];
  __shared__ __attribute__((aligned(16))) u16 lB[128 * 32];
  const int z = blockIdx.z;
  const u16* A = (z == 0) ? qbf : sbf;
  const u16* B = (z == 0) ? wqT : (z == 1) ? wkT : wvT;
  float* C = (z == 0) ? Qp : (z == 1) ? Kp : Vn;
  gemm128(A, B, C, nullptr, 256, 256, (z == 2) ? 2 : 1, lA, lB);
}

// merge: grid (32, 2)
__global__ __launch_bounds__(256) void merge_kernel(
    const u16* __restrict__ msg2, const u16* __restrict__ wmT, u16* __restrict__ merged)
{
  __shared__ __attribute__((aligned(16))) u16 lA[128 * 32];
  __shared__ __attribute__((aligned(16))) u16 lB[128 * 32];
  gemm128(msg2, wmT, nullptr, merged, 256, 256, 3, lA, lB);
}

// ---------------------------------------------------------------------------
// MLP1: hid[r][n] = relu(cat(xbf,ub)[r] . w1T[n]),  r: 128-rows/blk, n: 256/blk
// 32x32x16 MFMA, BK=64, XOR-swizzled LDS, grid (2, Mrows/128)
// ---------------------------------------------------------------------------
__global__ __launch_bounds__(256, 2) void mlp1_kernel(
    const u16* __restrict__ xbf, const u16* __restrict__ ub,
    const u16* __restrict__ w1T, u16* __restrict__ hid)
{
  __shared__ __attribute__((aligned(16))) u16 lA[128 * 64];  // 16 KB
  __shared__ __attribute__((aligned(16))) u16 lB[256 * 64];  // 32 KB
  const int tid = threadIdx.x;
  const int w = tid >> 6, l = tid & 63;
  const int wi = w >> 1, wj = w & 1;
  const int n0 = blockIdx.x * 256;
  const int m0 = blockIdx.y * 128;
  const int sr8 = l >> 3;          // row-within-8 for staging
  const int kbg = (l & 7) ^ sr8;   // swizzled global k-block

  f32x16 acc[2][4];
#pragma unroll
  for (int ti = 0; ti < 2; ++ti)
#pragma unroll
    for (int tj = 0; tj < 4; ++tj)
#pragma unroll
      for (int e = 0; e < 16; ++e) acc[ti][tj][e] = 0.f;

  for (int kc = 0; kc < 8; ++kc) {
    const u16* Asrc = (kc < 4) ? (xbf + kc * 64) : (ub + (kc - 4) * 64);
    __syncthreads();
#pragma unroll
    for (int it = 0; it < 4; ++it) {
      const int r = it * 32 + w * 8 + sr8;
      load_lds16(Asrc + (size_t)(m0 + r) * 256 + kbg * 8, &lA[(it * 32 + w * 8) * 64]);
    }
#pragma unroll
    for (int it = 0; it < 8; ++it) {
      const int r = it * 32 + w * 8 + sr8;
      load_lds16(w1T + (size_t)(n0 + r) * 512 + kc * 64 + kbg * 8, &lB[(it * 32 + w * 8) * 64]);
    }
    asm volatile("s_waitcnt vmcnt(0)" ::: "memory");
    __syncthreads();
    const int h = l >> 5;
#pragma unroll
    for (int s = 0; s < 4; ++s) {
      const int kb = s * 2 + h;
      bf16x8 af[2], bfr[4];
#pragma unroll
      for (int ti = 0; ti < 2; ++ti) {
        const int rt = wi * 64 + ti * 32 + (l & 31);
        af[ti] = *(const bf16x8*)&lA[rt * 64 + (kb ^ (rt & 7)) * 8];
      }
#pragma unroll
      for (int tj = 0; tj < 4; ++tj) {
        const int rn = wj * 128 + tj * 32 + (l & 31);
        bfr[tj] = *(const bf16x8*)&lB[rn * 64 + (kb ^ (rn & 7)) * 8];
      }
#pragma unroll
      for (int ti = 0; ti < 2; ++ti)
#pragma unroll
        for (int tj = 0; tj < 4; ++tj)
          acc[ti][tj] = __builtin_amdgcn_mfma_f32_32x32x16_bf16(af[ti], bfr[tj], acc[ti][tj], 0, 0, 0);
    }
  }

  const int h = l >> 5;
#pragma unroll
  for (int ti = 0; ti < 2; ++ti)
#pragma unroll
    for (int tj = 0; tj < 4; ++tj)
#pragma unroll
      for (int rg = 0; rg < 16; ++rg) {
        const int row = m0 + wi * 64 + ti * 32 + (rg & 3) + 8 * (rg >> 2) + 4 * h;
        const int col = n0 + wj * 128 + tj * 32 + (l & 31);
        const float v = acc[ti][tj][rg];
        hid[(size_t)row * 512 + col] = f2bf(v > 0.f ? v : 0.f);
      }
}

// ---------------------------------------------------------------------------
// MLP2 fused: m = hid @ w2T, then LN(m)*g+b + x residual -> out (NCHW).
// 64-pixel tile x 256 cols, K=512. grid (Mrows/64). pixbase = b0*16384.
// ---------------------------------------------------------------------------
__global__ __launch_bounds__(256, 3) void mlp2_kernel(
    const u16* __restrict__ hid, const u16* __restrict__ w2T,
    const float* __restrict__ x, const float* __restrict__ g,
    const float* __restrict__ bb, float* __restrict__ out, int pixbase)
{
  __shared__ __attribute__((aligned(16))) u16 lds[64 * 64 + 256 * 64];  // 40 KB
  __shared__ float redA[64][4];
  __shared__ float redB[64][4];
  __shared__ float statm[64], statr[64];
  u16* lA = lds;
  u16* lB = lds + 64 * 64;
  u16* sm = lds;  // reused after K-loop: 64 x 258 bf16 = 33 KB

  const int tid = threadIdx.x;
  const int w = tid >> 6, l = tid & 63;
  const int m0 = blockIdx.x * 64;
  const int sr8 = l >> 3;
  const int kbg = (l & 7) ^ sr8;

  f32x16 acc[2][2];
#pragma unroll
  for (int ti = 0; ti < 2; ++ti)
#pragma unroll
    for (int tj = 0; tj < 2; ++tj)
#pragma unroll
      for (int e = 0; e < 16; ++e) acc[ti][tj][e] = 0.f;

  for (int kc = 0; kc < 8; ++kc) {
    __syncthreads();
#pragma unroll
    for (int it = 0; it < 2; ++it) {
      const int r = it * 32 + w * 8 + sr8;
      load_lds16(hid + (size_t)(m0 + r) * 512 + kc * 64 + kbg * 8, &lA[(it * 32 + w * 8) * 64]);
    }
#pragma unroll
    for (int it = 0; it < 8; ++it) {
      const int r = it * 32 + w * 8 + sr8;
      load_lds16(w2T + (size_t)r * 512 + kc * 64 + kbg * 8, &lB[(it * 32 + w * 8) * 64]);
    }
    asm volatile("s_waitcnt vmcnt(0)" ::: "memory");
    __syncthreads();
    const int h = l >> 5;
#pragma unroll
    for (int s = 0; s < 4; ++s) {
      const int kb = s * 2 + h;
      bf16x8 af[2], bfr[2];
#pragma unroll
      for (int ti = 0; ti < 2; ++ti) {
        const int rt = ti * 32 + (l & 31);
        af[ti] = *(const bf16x8*)&lA[rt * 64 + (kb ^ (rt & 7)) * 8];
      }
#pragma unroll
      for (int tj = 0; tj < 2; ++tj) {
        const int rn = w * 64 + tj * 32 + (l & 31);
        bfr[tj] = *(const bf16x8*)&lB[rn * 64 + (kb ^ (rn & 7)) * 8];
      }
#pragma unroll
      for (int ti = 0; ti < 2; ++ti)
#pragma unroll
        for (int tj = 0; tj < 2; ++tj)
          acc[ti][tj] = __builtin_amdgcn_mfma_f32_32x32x16_bf16(af[ti], bfr[tj], acc[ti][tj], 0, 0, 0);
    }
  }

  __syncthreads();
  {
    const int h = l >> 5;
#pragma unroll
    for (int ti = 0; ti < 2; ++ti)
#pragma unroll
      for (int tj = 0; tj < 2; ++tj)
#pragma unroll
        for (int rg = 0; rg < 16; ++rg) {
          const int prow = ti * 32 + (rg & 3) + 8 * (rg >> 2) + 4 * h;
          const int pcol = w * 64 + tj * 32 + (l & 31);
          sm[prow * 258 + pcol] = f2bf(acc[ti][tj][rg]);
        }
  }
  __syncthreads();
  {
    const int p = tid & 63, q = tid >> 6;
    float s = 0.f, s2 = 0.f;
    for (int k = 0; k < 64; ++k) {
      const float v = bf2f(sm[p * 258 + q * 64 + k]);
      s += v; s2 += v * v;
    }
    redA[p][q] = s; redB[p][q] = s2;
  }
  __syncthreads();
  if (tid < 64) {
    const float ss = redA[tid][0] + redA[tid][1] + redA[tid][2] + redA[tid][3];
    const float qq = redB[tid][0] + redB[tid][1] + redB[tid][2] + redB[tid][3];
    const float mean = ss * (1.f / 256.f);
    const float var = qq * (1.f / 256.f) - mean * mean;
    statm[tid] = mean;
    statr[tid] = rsqrtf(var + 1e-5f);
  }
  __syncthreads();
  {
    const int gp = pixbase + m0;
    const int b = gp >> 14;
    const int rem = gp & 16383;
    const int i = rem >> 7;
    const int j0 = rem & 127;
    const int p = tid & 63, cg = tid >> 6;
    const int j = j0 + p;
    const float mu = statm[p], rs = statr[p];
    for (int k = 0; k < 64; ++k) {
      const int c = cg * 64 + k;
      const float v = (bf2f(sm[p * 258 + c]) - mu) * rs * g[c] + bb[c];
      const size_t oi = (((size_t)b * 256 + c) * 128 + i) * 128 + j;
      out[oi] = x[oi] + v;
    }
  }
}

// ---------------------------------------------------------------------------
// Weight transpose + bf16 cast: w[K][N] fp32 -> wt[N][K] bf16 (64x64 tiles)
// ---------------------------------------------------------------------------
__global__ __launch_bounds__(256) void transpose_w_kernel(
    const float* __restrict__ wq, const float* __restrict__ wk,
    const float* __restrict__ wv, const float* __restrict__ wm,
    const float* __restrict__ w1, const float* __restrict__ w2,
    u16* __restrict__ oq, u16* __restrict__ okk, u16* __restrict__ ov,
    u16* __restrict__ om, u16* __restrict__ o1, u16* __restrict__ o2)
{
  __shared__ float ts[64][65];
  int bid = blockIdx.x;
  const float* src; u16* dst; int K, N, t;
  if (bid < 64) {
    int wsel = bid >> 4; t = bid & 15; K = 256; N = 256;
    src = wsel == 0 ? wq : wsel == 1 ? wk : wsel == 2 ? wv : wm;
    dst = wsel == 0 ? oq : wsel == 1 ? okk : wsel == 2 ? ov : om;
  } else if (bid < 128) { t = bid - 64; K = 512; N = 512; src = w1; dst = o1; }
  else                  { t = bid - 128; K = 512; N = 256; src = w2; dst = o2; }
  const int ntn = N >> 6;
  const int tn = t % ntn, tk = t / ntn;
  const int tid = threadIdx.x, ln = tid & 63, lrr = tid >> 6;
  for (int k = 0; k < 64; k += 4)
    ts[k + lrr][ln] = src[(size_t)(tk * 64 + k + lrr) * N + tn * 64 + ln];
  __syncthreads();
  for (int k = 0; k < 64; k += 4)
    dst[(size_t)(tn * 64 + k + lrr) * K + tk * 64 + ln] = f2bf(ts[ln][k + lrr]);
}

// ---------------------------------------------------------------------------
// Fused 4x4 maxpool (NCHW) + layernorm over C -> bf16 rows
// ---------------------------------------------------------------------------
__global__ __launch_bounds__(256) void pool_ln_kernel(
    const float* __restrict__ x, const float* __restrict__ src,
    const float* __restrict__ g, const float* __restrict__ bb,
    u16* __restrict__ qout, u16* __restrict__ sout)
{
  __shared__ float pool[256 * 33];
  __shared__ float redA[8][32];
  __shared__ float redB[8][32];
  __shared__ float stat_m[32];
  __shared__ float stat_r[32];
  const int ph = blockIdx.x, b = blockIdx.y;
  const float* in = blockIdx.z ? src : x;
  u16* out = blockIdx.z ? sout : qout;
  const int tid = threadIdx.x;
  const int pw = tid & 31, cg = tid >> 5;
  for (int kk = 0; kk < 32; ++kk) {
    const int c = cg * 32 + kk;
    const float* base = in + (((size_t)b * 256 + c) * 128 + ph * 4) * 128 + pw * 4;
    float4 v0 = *(const float4*)(base);
    float4 v1 = *(const float4*)(base + 128);
    float4 v2 = *(const float4*)(base + 256);
    float4 v3 = *(const float4*)(base + 384);
    float m = fmaxf(fmaxf(fmaxf(v0.x, v0.y), fmaxf(v0.z, v0.w)),
                    fmaxf(fmaxf(v1.x, v1.y), fmaxf(v1.z, v1.w)));
    m = fmaxf(m, fmaxf(fmaxf(v2.x, v2.y), fmaxf(v2.z, v2.w)));
    m = fmaxf(m, fmaxf(fmaxf(v3.x, v3.y), fmaxf(v3.z, v3.w)));
    pool[c * 33 + pw] = m;
  }
  __syncthreads();
  float s = 0.f, s2 = 0.f;
  for (int i = 0; i < 32; ++i) {
    float v = pool[(cg * 32 + i) * 33 + pw];
    s += v; s2 += v * v;
  }
  redA[cg][pw] = s; redB[cg][pw] = s2;
  __syncthreads();
  if (tid < 32) {
    float ss = 0.f, ss2 = 0.f;
    for (int i = 0; i < 8; ++i) { ss += redA[i][tid]; ss2 += redB[i][tid]; }
    float mean = ss * (1.f / 256.f);
    float var = ss2 * (1.f / 256.f) - mean * mean;
    stat_m[tid] = mean;
    stat_r[tid] = rsqrtf(var + 1e-5f);
  }
  __syncthreads();
  const float gc = g[tid], bc = bb[tid];
  const size_t rowbase = ((size_t)b * 1024 + ph * 32) * 256;
  for (int p = 0; p < 32; ++p) {
    float v = (pool[tid * 33 + p] - stat_m[p]) * stat_r[p] * gc + bc;
    out[rowbase + (size_t)p * 256 + tid] = f2bf(v);
  }
}

// ---------------------------------------------------------------------------
// KV[d][v] + Ksum[d] per (b,h). grid (8 h, 4 b)
// ---------------------------------------------------------------------------
__global__ __launch_bounds__(256) void kv_kernel(
    const float* __restrict__ Kp, const float* __restrict__ Vn,
    float* __restrict__ kvbuf)
{
  __shared__ float kch[128 * 33];
  __shared__ float vch[128 * 33];
  const int h = blockIdx.x, b = blockIdx.y;
  const int tid = threadIdx.x;
  const int d = tid & 31, sl = tid >> 5;
  const int v = tid & 31, dp = tid >> 5;
  float a0 = 0.f, a1 = 0.f, a2 = 0.f, a3 = 0.f, ks = 0.f;
  for (int ch = 0; ch < 8; ++ch) {
    __syncthreads();
    for (int ss = 0; ss < 16; ++ss) {
      const int srow = ch * 128 + ss * 8 + sl;
      const size_t gi = ((size_t)b * 1024 + srow) * 256 + h * 32 + d;
      kch[(ss * 8 + sl) * 33 + d] = Kp[gi];
      vch[(ss * 8 + sl) * 33 + d] = Vn[gi];
    }
    __syncthreads();
    for (int s = 0; s < 128; ++s) {
      const float vv = vch[s * 33 + v];
      a0 += kch[s * 33 + dp] * vv;
      a1 += kch[s * 33 + dp + 8] * vv;
      a2 += kch[s * 33 + dp + 16] * vv;
      a3 += kch[s * 33 + dp + 24] * vv;
    }
    if (tid < 32)
      for (int s = 0; s < 128; ++s) ks += kch[s * 33 + tid];
  }
  float* outp = kvbuf + ((size_t)b * 8 + h) * 1056;
  outp[(dp) * 32 + v]      = a0;
  outp[(dp + 8) * 32 + v]  = a1;
  outp[(dp + 16) * 32 + v] = a2;
  outp[(dp + 24) * 32 + v] = a3;
  if (tid < 32) outp[1024 + tid] = ks;
}

// ---------------------------------------------------------------------------
// msg[l,h,v] = (Qp[l].KV[:,v]) * 1024 / (Qp[l].Ksum + 1e-6) -> bf16
// ---------------------------------------------------------------------------
__global__ __launch_bounds__(256) void msg_kernel(
    const float* __restrict__ Qp, const float* __restrict__ kvbuf,
    u16* __restrict__ msg2)
{
  __shared__ float kv[32 * 33];
  __shared__ float ksum[32];
  __shared__ float qch[8 * 33];
  const int lc = blockIdx.x, h = blockIdx.y, b = blockIdx.z;
  const int tid = threadIdx.x;
  const float* kvp = kvbuf + ((size_t)b * 8 + h) * 1056;
  for (int i = tid; i < 1024; i += 256) kv[(i >> 5) * 33 + (i & 31)] = kvp[i];
  if (tid < 32) ksum[tid] = kvp[1024 + tid];
  const int d = tid & 31, lr = tid >> 5;
  const int v = tid & 31;
  for (int ps = 0; ps < 8; ++ps) {
    __syncthreads();
    const int l = lc * 64 + ps * 8 + lr;
    qch[lr * 33 + d] = Qp[((size_t)b * 1024 + l) * 256 + h * 32 + d];
    __syncthreads();
    float dot = 0.f, zden = 0.f;
    for (int dd = 0; dd < 32; ++dd) {
      const float q = qch[lr * 33 + dd];
      dot  += q * kv[dd * 33 + v];
      zden += q * ksum[dd];
    }
    const float m = dot * (1024.f / (zden + 1e-6f));
    msg2[((size_t)b * 1024 + l) * 256 + h * 32 + v] = f2bf(m);
  }
}

// ---------------------------------------------------------------------------
// Prep: y<4 -> x NCHW fp32 -> xbf NHWC bf16 ; y==4 -> bilinear upsample -> ub
// grid (2 jc, 5 y, 128*nb), block 256
// ---------------------------------------------------------------------------
__global__ __launch_bounds__(256) void prep_kernel(
    const float* __restrict__ x, const u16* __restrict__ merged,
    u16* __restrict__ xbf, u16* __restrict__ ub, int b0)
{
  __shared__ float ts[64][65];
  const int jc = blockIdx.x, y = blockIdx.y, iz = blockIdx.z;
  const int localb = iz >> 7;
  const int b = b0 + localb;
  const int i = iz & 127;
  const int tid = threadIdx.x;
  if (y < 4) {
    const int cc = y, ln = tid & 63, lrr = tid >> 6;
    const float* xp = x + (size_t)b * 256 * 16384;
    for (int k = 0; k < 64; k += 4)
      ts[k + lrr][ln] = xp[((size_t)(cc * 64 + k + lrr) * 128 + i) * 128 + jc * 64 + ln];
    __syncthreads();
    for (int k = 0; k < 64; k += 4) {
      const size_t row = (size_t)localb * 16384 + (size_t)i * 128 + jc * 64 + k + lrr;
      xbf[row * 256 + cc * 64 + ln] = f2bf(ts[ln][k + lrr]);
    }
  } else {
    const float sy = 0.25f * i - 0.375f;
    const float fy = floorf(sy);
    const float wy = sy - fy;
    const int y0 = max(0, min(31, (int)fy));
    const int y1 = max(0, min(31, (int)fy + 1));
    const u16* mb = merged + (size_t)b * 1024 * 256;
    for (int p = 0; p < 64; ++p) {
      const int j = jc * 64 + p;
      const float sx = 0.25f * j - 0.375f;
      const float fx = floorf(sx);
      const float wx = sx - fx;
      const int x0 = max(0, min(31, (int)fx));
      const int x1 = max(0, min(31, (int)fx + 1));
      const u16* r00 = mb + ((size_t)y0 * 32 + x0) * 256;
      const u16* r01 = mb + ((size_t)y0 * 32 + x1) * 256;
      const u16* r10 = mb + ((size_t)y1 * 32 + x0) * 256;
      const u16* r11 = mb + ((size_t)y1 * 32 + x1) * 256;
      const float v = (1.f - wy) * ((1.f - wx) * bf2f(r00[tid]) + wx * bf2f(r01[tid]))
                    +        wy  * ((1.f - wx) * bf2f(r10[tid]) + wx * bf2f(r11[tid]));
      const size_t row = (size_t)localb * 16384 + (size_t)i * 128 + j;
      ub[row * 256 + tid] = f2bf(v);
    }
  }
}

// ---------------------------------------------------------------------------
extern "C" void kernel_launch(void* const* d_in, const int* in_sizes, int n_in,
                              void* d_out, int out_size, void* d_ws, size_t ws_size,
                              hipStream_t stream) {
  (void)in_sizes; (void)n_in; (void)out_size;
  const float* x   = (const float*)d_in[0];
  const float* src = (const float*)d_in[1];
  const float* n1g = (const float*)d_in[2];
  const float* n1b = (const float*)d_in[3];
  const float* w_q = (const float*)d_in[4];
  const float* w_k = (const float*)d_in[5];
  const float* w_v = (const float*)d_in[6];
  const float* w_m = (const float*)d_in[7];
  const float* w1  = (const float*)d_in[8];
  const float* w2  = (const float*)d_in[9];
  const float* n2g = (const float*)d_in[10];
  const float* n2b = (const float*)d_in[11];
  float* out = (float*)d_out;

  char* ws = (char*)d_ws;
  size_t off = 0;
  auto alloc = [&](size_t bytes) -> void* {
    void* p = ws + off;
    off = (off + bytes + 255) & ~(size_t)255;
    return p;
  };
  u16* wqT = (u16*)alloc(256 * 256 * 2);
  u16* wkT = (u16*)alloc(256 * 256 * 2);
  u16* wvT = (u16*)alloc(256 * 256 * 2);
  u16* wmT = (u16*)alloc(256 * 256 * 2);
  u16* w1T = (u16*)alloc(512 * 512 * 2);
  u16* w2T = (u16*)alloc(256 * 512 * 2);
  u16* qbf = (u16*)alloc((size_t)4096 * 256 * 2);
  u16* sbf = (u16*)alloc((size_t)4096 * 256 * 2);
  float* Qp = (float*)alloc((size_t)4096 * 256 * 4);
  float* Kp = (float*)alloc((size_t)4096 * 256 * 4);
  float* Vn = (float*)alloc((size_t)4096 * 256 * 4);
  float* kvb = (float*)alloc((size_t)32 * 1056 * 4);
  u16* msg2   = (u16*)alloc((size_t)4096 * 256 * 2);
  u16* merged = (u16*)alloc((size_t)4096 * 256 * 2);

  size_t remain = (ws_size > off) ? ws_size - off : 0;
  auto need = [](int nb) { return (size_t)nb * 16384 * (256 + 256 + 512) * 2 + 4096; };
  int nb = (remain >= need(4)) ? 4 : (remain >= need(2)) ? 2 : 1;
  u16* xbf = (u16*)alloc((size_t)nb * 16384 * 256 * 2);
  u16* ub  = (u16*)alloc((size_t)nb * 16384 * 256 * 2);
  u16* hid = (u16*)alloc((size_t)nb * 16384 * 512 * 2);

  transpose_w_kernel<<<dim3(160), dim3(256), 0, stream>>>(
      w_q, w_k, w_v, w_m, w1, w2, wqT, wkT, wvT, wmT, w1T, w2T);

  pool_ln_kernel<<<dim3(32, 4, 2), dim3(256), 0, stream>>>(
      x, src, n1g, n1b, qbf, sbf);

  qkv_kernel<<<dim3(32, 2, 3), dim3(256), 0, stream>>>(
      qbf, sbf, wqT, wkT, wvT, Qp, Kp, Vn);

  kv_kernel<<<dim3(8, 4), dim3(256), 0, stream>>>(Kp, Vn, kvb);
  msg_kernel<<<dim3(16, 8, 4), dim3(256), 0, stream>>>(Qp, kvb, msg2);

  merge_kernel<<<dim3(32, 2), dim3(256), 0, stream>>>(msg2, wmT, merged);

  for (int b0 = 0; b0 < 4; b0 += nb) {
    prep_kernel<<<dim3(2, 5, 128 * nb), dim3(256), 0, stream>>>(
        x, merged, xbf, ub, b0);
    mlp1_kernel<<<dim3(2, nb * 128), dim3(256), 0, stream>>>(
        xbf, ub, w1T, hid);
    mlp2_kernel<<<dim3(nb * 256), dim3(256), 0, stream>>>(
        hid, w2T, x, n2g, n2b, out, b0 * 16384);
  }
}